// Round 7
// baseline (66.772 us; speedup 1.0000x reference)
//
#include <hip/hip_runtime.h>
#include <hip/hip_bf16.h>

// B=512, T=256, C=384, H=64 single-head causal attention.
// Round 6: 8-wave fused kernel, M=32/wave GEMM, 3-deep prefetch ring.
//   prep_bt: W -> Bt[192][384] bf16 in ws.
//   fused  : grid 512 (block = batch), 512 threads (8 waves), 1 block/CU.
//     Bt staged in LDS [192][392] (150.5 KB, overlaid by attn tiles later).
//     GEMM: wave w owns rows [32w,32w+32) x N=192; A direct global->reg,
//       3-chunk lookahead (no barriers in K-loop); each B ds_read feeds
//       2 MFMAs (halved LDS traffic vs round 5). acc = 2x12 f32x4.
//     Epilogue -> LDS overlay: q (xSCALE) -> qs[256][64] swz; K -> kl swz;
//       V -> vt[64][256] swz (uint2).
//     Attn: wave w owns strips {16w, 240-16w} -> exactly 5 tiles/wave.
//       P buffer = qs rows [16w,16w+16) (own strip-0 Q rows; no cross-wave
//       hazard: strip-1 Q rows are >=128, P regions are <128).

constexpr int BSZ  = 512;
constexpr int TT   = 256;
constexpr int CDIM = 384;
constexpr int HDIM = 64;
constexpr int NQKV = 192;
constexpr float SCALE = 0.051031036307982884f;  // 384^-0.5 (C, not head size)
constexpr int BTST = 392;   // Bt LDS row stride (784 B, 16B-aligned, mild banks)

typedef __attribute__((ext_vector_type(8))) short bf16x8;
typedef __attribute__((ext_vector_type(4))) float f32x4;

__device__ inline unsigned short f2bf(float f) {
    __hip_bfloat16 h = __float2bfloat16(f);
    return *(unsigned short*)&h;
}
__device__ inline bf16x8 pack8(float4 a, float4 b) {
    unsigned short p[8] = { f2bf(a.x), f2bf(a.y), f2bf(a.z), f2bf(a.w),
                            f2bf(b.x), f2bf(b.y), f2bf(b.z), f2bf(b.w) };
    return *(bf16x8*)p;
}

// ---------------- kernel 0: Bt[192][384] bf16 = [Wq|Wk|Wv]^T ----------------
__global__ __launch_bounds__(256) void prep_bt(
    const float* __restrict__ Wq, const float* __restrict__ Wk,
    const float* __restrict__ Wv, unsigned short* __restrict__ bt)
{
    int idx = blockIdx.x * 256 + threadIdx.x;
    if (idx >= NQKV * CDIM) return;
    int n = idx / CDIM, k = idx - n * CDIM;
    const float* W = (n < 64) ? Wq : (n < 128) ? Wk : Wv;
    bt[idx] = f2bf(W[(size_t)k * HDIM + (n & 63)]);
}

// ---------------- fused QKV-projection + flash attention ----------------
__global__ __launch_bounds__(512, 2) void fused(
    const float* __restrict__ x, const unsigned short* __restrict__ bt,
    float* __restrict__ out)
{
    // GEMM phase: smem = Bt [192][392] (150,528 B)
    // attn phase overlay: qs[256][64] (q, then P) | kl[256][64] | vt[64][256]
    __shared__ __align__(16) unsigned short smem[NQKV * BTST];
    unsigned short* btl = smem;
    unsigned short* qs  = smem;
    unsigned short* kl  = smem + 16384;
    unsigned short* vt  = smem + 32768;

    const int b = blockIdx.x, tid = threadIdx.x;
    const int w = tid >> 6, lane = tid & 63;
    const int lr = lane & 15, lk = lane >> 4;
    const float* xb = x + (size_t)b * TT * CDIM;

    // ---- stage Bt into LDS: 9216 uint4, 18 per thread, coalesced ----
    #pragma unroll
    for (int p = 0; p < 18; ++p) {
        int i = p * 512 + tid;
        int row = i / 48, c8 = i - row * 48;
        *(uint4*)&btl[row * BTST + c8 * 8] = ((const uint4*)bt)[i];
    }
    __syncthreads();

    // ---- GEMM: wave w -> rows [32w, 32w+32) x 192, K = 384 ----
    const int m0 = 32 * w;
    const float* xr0 = xb + (size_t)(m0 + lr) * CDIM + lk * 8;
    const float* xr1 = xr0 + 16 * CDIM;

    f32x4 acc0[12], acc1[12];
    #pragma unroll
    for (int ni = 0; ni < 12; ++ni) {
        acc0[ni] = (f32x4){0.f, 0.f, 0.f, 0.f};
        acc1[ni] = (f32x4){0.f, 0.f, 0.f, 0.f};
    }

    float4 pf0[4], pf1[4], pf2[4];
#define LDCH(P, ks) { \
    P[0] = *(const float4*)&xr0[(ks) * 32];     \
    P[1] = *(const float4*)&xr0[(ks) * 32 + 4]; \
    P[2] = *(const float4*)&xr1[(ks) * 32];     \
    P[3] = *(const float4*)&xr1[(ks) * 32 + 4]; }
#define STEP(P, ks, cond) { \
    bf16x8 a0 = pack8(P[0], P[1]); \
    bf16x8 a1 = pack8(P[2], P[3]); \
    if (cond) LDCH(P, (ks) + 3); \
    _Pragma("unroll") \
    for (int ni = 0; ni < 12; ++ni) { \
        bf16x8 bb = *(const bf16x8*)&btl[(ni * 16 + lr) * BTST + (ks) * 32 + lk * 8]; \
        acc0[ni] = __builtin_amdgcn_mfma_f32_16x16x32_bf16(a0, bb, acc0[ni], 0, 0, 0); \
        acc1[ni] = __builtin_amdgcn_mfma_f32_16x16x32_bf16(a1, bb, acc1[ni], 0, 0, 0); \
    } }

    LDCH(pf0, 0) LDCH(pf1, 1) LDCH(pf2, 2)
    #pragma unroll
    for (int kk = 0; kk < 4; ++kk) {
        STEP(pf0, 3 * kk + 0, kk < 3)
        STEP(pf1, 3 * kk + 1, kk < 3)
        STEP(pf2, 3 * kk + 2, kk < 3)
    }
#undef LDCH
#undef STEP
    __syncthreads();   // all Bt reads done before overlay writes

    // ---- epilogue: D-frags -> LDS homes. D: col=ni*16+lr, row=m0+mi*16+lk*4+r
    #pragma unroll
    for (int mi = 0; mi < 2; ++mi) {
        const f32x4* am = mi ? acc1 : acc0;
        #pragma unroll
        for (int ni = 0; ni < 4; ++ni)          // q: cols 0..63, pre-scaled
            #pragma unroll
            for (int r = 0; r < 4; ++r) {
                int row = m0 + mi * 16 + lk * 4 + r;
                int h   = ni * 16 + lr;
                qs[row * 64 + (h ^ ((row & 7) << 3))] = f2bf(am[ni][r] * SCALE);
            }
        #pragma unroll
        for (int ni = 4; ni < 8; ++ni)          // k -> kl[t][h] swz
            #pragma unroll
            for (int r = 0; r < 4; ++r) {
                int row = m0 + mi * 16 + lk * 4 + r;
                int c2  = (ni - 4) * 16 + lr;
                kl[row * 64 + (c2 ^ ((row & 7) << 3))] = f2bf(am[ni][r]);
            }
        #pragma unroll
        for (int ni = 8; ni < 12; ++ni) {       // v -> vt[h][t] swz, uint2
            int h  = (ni - 8) * 16 + lr;
            int t0 = m0 + mi * 16 + lk * 4;
            unsigned short pk[4];
            #pragma unroll
            for (int r = 0; r < 4; ++r) pk[r] = f2bf(am[ni][r]);
            *(uint2*)&vt[h * 256 + (t0 ^ ((h & 7) << 3))] = *(uint2*)pk;
        }
    }
    __syncthreads();

    // ---- attention: wave w owns strips {16w, 240-16w}, 5 tiles total ----
    const int q0a[2]  = {16 * w, 240 - 16 * w};
    const int lastA[2] = {(q0a[0] + 15) >> 6, (q0a[1] + 15) >> 6};

    bf16x8 qa[2][2];
    #pragma unroll
    for (int s2 = 0; s2 < 2; ++s2)
        #pragma unroll
        for (int kc = 0; kc < 2; ++kc)
            qa[s2][kc] = *(const bf16x8*)
                &qs[(q0a[s2] + lr) * 64 + ((kc * 32 + lk * 8) ^ ((lr & 7) << 3))];
    // P region = qs rows [16w,16w+16): own strip-0 Q (read above, same-wave
    // DS ordering); strip-1 Q rows are >=128, never a P region -> no barrier.
    unsigned short* pb = qs + w * 1024;

    f32x4 oacc[2][4];
    float mrow[2][4], lpart[2][4];
    #pragma unroll
    for (int s2 = 0; s2 < 2; ++s2) {
        #pragma unroll
        for (int nh = 0; nh < 4; ++nh) oacc[s2][nh] = (f32x4){0.f, 0.f, 0.f, 0.f};
        #pragma unroll
        for (int r = 0; r < 4; ++r) { mrow[s2][r] = -INFINITY; lpart[s2][r] = 0.f; }
    }

    for (int st = 0; st <= lastA[1]; ++st) {
        #pragma unroll
        for (int s2 = 0; s2 < 2; ++s2) {
            if (st > lastA[s2]) continue;
            const int q0 = q0a[s2];

            // S = Q K^T
            f32x4 sa[4];
            #pragma unroll
            for (int ni = 0; ni < 4; ++ni) sa[ni] = (f32x4){0.f, 0.f, 0.f, 0.f};
            #pragma unroll
            for (int ni = 0; ni < 4; ++ni) {
                int row = st * 64 + ni * 16 + lr;
                #pragma unroll
                for (int kc = 0; kc < 2; ++kc) {
                    bf16x8 kb = *(const bf16x8*)
                        &kl[row * 64 + ((kc * 32 + lk * 8) ^ ((lr & 7) << 3))];
                    sa[ni] = __builtin_amdgcn_mfma_f32_16x16x32_bf16(
                        qa[s2][kc], kb, sa[ni], 0, 0, 0);
                }
            }
            // causal mask (diagonal tile only)
            if (st == lastA[s2]) {
                #pragma unroll
                for (int ni = 0; ni < 4; ++ni) {
                    int sg = st * 64 + ni * 16 + lr;
                    #pragma unroll
                    for (int r = 0; r < 4; ++r) {
                        int qg = q0 + lk * 4 + r;
                        if (sg > qg) sa[ni][r] = -INFINITY;
                    }
                }
            }
            // row max over ni, then over lr
            float pm[4];
            #pragma unroll
            for (int r = 0; r < 4; ++r)
                pm[r] = fmaxf(fmaxf(sa[0][r], sa[1][r]), fmaxf(sa[2][r], sa[3][r]));
            #pragma unroll
            for (int stp = 1; stp < 16; stp <<= 1)
                #pragma unroll
                for (int r = 0; r < 4; ++r)
                    pm[r] = fmaxf(pm[r], __shfl_xor(pm[r], stp));
            // online update
            float mnew[4];
            #pragma unroll
            for (int r = 0; r < 4; ++r) {
                float mn = fmaxf(mrow[s2][r], pm[r]);
                float corr = __expf(mrow[s2][r] - mn);   // exp(-inf)=0 first time
                mrow[s2][r] = mn; mnew[r] = mn;
                lpart[s2][r] *= corr;
                #pragma unroll
                for (int nh = 0; nh < 4; ++nh) oacc[s2][nh][r] *= corr;
            }
            // P = exp(S - m) -> wave-private swizzled LDS
            #pragma unroll
            for (int ni = 0; ni < 4; ++ni) {
                int s = ni * 16 + lr;
                #pragma unroll
                for (int r = 0; r < 4; ++r) {
                    float p = __expf(sa[ni][r] - mnew[r]);
                    lpart[s2][r] += p;
                    int qr = lk * 4 + r;
                    pb[qr * 64 + (s ^ ((qr & 7) << 3))] = f2bf(p);
                }
            }
            // PV
            bf16x8 pa[2];
            #pragma unroll
            for (int kc = 0; kc < 2; ++kc)
                pa[kc] = *(const bf16x8*)
                    &pb[lr * 64 + ((kc * 32 + lk * 8) ^ ((lr & 7) << 3))];
            #pragma unroll
            for (int nh = 0; nh < 4; ++nh) {
                int hrow = nh * 16 + lr;
                #pragma unroll
                for (int kc = 0; kc < 2; ++kc) {
                    bf16x8 vb = *(const bf16x8*)
                        &vt[hrow * 256 + ((st * 64 + kc * 32 + lk * 8) ^ ((hrow & 7) << 3))];
                    oacc[s2][nh] = __builtin_amdgcn_mfma_f32_16x16x32_bf16(
                        pa[kc], vb, oacc[s2][nh], 0, 0, 0);
                }
            }
        }
    }

    // ---- finalize ----
    #pragma unroll
    for (int s2 = 0; s2 < 2; ++s2) {
        float linv[4];
        #pragma unroll
        for (int r = 0; r < 4; ++r) {
            float l = lpart[s2][r];
            #pragma unroll
            for (int stp = 1; stp < 16; stp <<= 1) l += __shfl_xor(l, stp);
            linv[r] = 1.0f / l;
        }
        #pragma unroll
        for (int nh = 0; nh < 4; ++nh)
            #pragma unroll
            for (int r = 0; r < 4; ++r) {
                size_t row = (size_t)b * TT + q0a[s2] + lk * 4 + r;
                out[row * HDIM + nh * 16 + lr] = oacc[s2][nh][r] * linv[r];
            }
    }
}

extern "C" void kernel_launch(void* const* d_in, const int* in_sizes, int n_in,
                              void* d_out, int out_size, void* d_ws, size_t ws_size,
                              hipStream_t stream)
{
    const float* x  = (const float*)d_in[0];
    const float* Wq = (const float*)d_in[1];
    const float* Wk = (const float*)d_in[2];
    const float* Wv = (const float*)d_in[3];
    unsigned short* bt = (unsigned short*)d_ws;   // [192][384] bf16 = 147 KB
    float* out = (float*)d_out;

    prep_bt<<<(NQKV * CDIM + 255) / 256, 256, 0, stream>>>(Wq, Wk, Wv, bt);
    fused<<<BSZ, 512, 0, stream>>>(x, bt, out);
}